// Round 1
// baseline (2979.778 us; speedup 1.0000x reference)
//
#include <hip/hip_runtime.h>
#include <math.h>

// Shapes (fixed by the problem)
//  L=512 B=4 D=1024 H=16 DH=64 FF=4096 HP=32 K=256, LK=L+K=768
//  MQ = L*B = 2048 rows, MKV = LK*B = 3072 rows

typedef __bf16 bf16x8 __attribute__((ext_vector_type(8)));
typedef float f32x4 __attribute__((ext_vector_type(4)));

__device__ __forceinline__ unsigned short f2bf(float f) {
  unsigned u = __float_as_uint(f);
  u = (u + 0x7fffu + ((u >> 16) & 1u)) >> 16;
  return (unsigned short)u;
}
__device__ __forceinline__ float bf2f(unsigned short s) {
  return __uint_as_float(((unsigned)s) << 16);
}

__device__ __forceinline__ void gload_lds16(const void* g, void* l) {
  __builtin_amdgcn_global_load_lds(
      (__attribute__((address_space(1))) void*)g,
      (__attribute__((address_space(3))) void*)l, 16, 0, 0);
}

// ---------------- transpose f32 -> bf16 (for NT GEMM B operands) -------------
__global__ __launch_bounds__(256) void transpose_bf16(
    const float* __restrict__ W, unsigned short* __restrict__ WT, int Kd, int Nd) {
  __shared__ float tile[32][33];
  const int n0 = blockIdx.x * 32, k0 = blockIdx.y * 32;
  const int tx = threadIdx.x, ty = threadIdx.y;  // 32 x 8
#pragma unroll
  for (int i = 0; i < 32; i += 8)
    tile[ty + i][tx] = W[(long)(k0 + ty + i) * Nd + n0 + tx];
  __syncthreads();
#pragma unroll
  for (int i = 0; i < 32; i += 8)
    WT[(long)(n0 + ty + i) * Kd + k0 + tx] = f2bf(tile[tx][ty + i]);
}

// ---------------- LayerNorm (f32 in, bf16 out), row = 1024 -------------------
__global__ __launch_bounds__(256) void ln_bf16(
    const float* __restrict__ X, unsigned short* __restrict__ Y,
    const float* __restrict__ g, const float* __restrict__ bb) {
  const int row = blockIdx.x, t = threadIdx.x;
  const float* xr = X + (long)row * 1024;
  float v[4]; float s = 0.f, ss = 0.f;
#pragma unroll
  for (int i = 0; i < 4; i++) { v[i] = xr[t + 256 * i]; s += v[i]; ss += v[i] * v[i]; }
#pragma unroll
  for (int o = 32; o > 0; o >>= 1) { s += __shfl_down(s, o); ss += __shfl_down(ss, o); }
  __shared__ float red[8];
  const int wave = t >> 6, lane = t & 63;
  if (lane == 0) { red[wave] = s; red[4 + wave] = ss; }
  __syncthreads();
  s = red[0] + red[1] + red[2] + red[3];
  ss = red[4] + red[5] + red[6] + red[7];
  const float mean = s * (1.f / 1024.f);
  const float rstd = rsqrtf(ss * (1.f / 1024.f) - mean * mean + 1e-5f);
#pragma unroll
  for (int i = 0; i < 4; i++) {
    const int c = t + 256 * i;
    Y[(long)row * 1024 + c] = f2bf((v[i] - mean) * rstd * g[c] + bb[c]);
  }
}

// -------- gather expanded rows of kv_src (bf16), rows [2048, 3072) -----------
__global__ __launch_bounds__(256) void gather_kv(unsigned short* kv, const int* __restrict__ oc) {
  int idx = blockIdx.x * 256 + threadIdx.x;  // 1024 rows * 256 ushort4 = 262144
  int col4 = idx & 255;
  int r = idx >> 8;        // 0..1023 = j*4+b
  int j = r >> 2, b = r & 3;
  int src = oc[b * 256 + j] * 4 + b;
  ((ushort4*)kv)[((512 + j) * 4 + b) * 256 + col4] = ((const ushort4*)kv)[src * 256 + col4];
}

// ---------------- MFMA bf16 NT GEMM, 128x128 tile, BK=32 (m97 structure) -----
// C[M,N] = A[M,K] * BT[N,K]^T ; EPI: 0 = f32 out, 1 = f32 out + R, 2 = bf16 gelu(out)
template <int EPI>
__global__ __launch_bounds__(256) void gemm_nt(
    const unsigned short* __restrict__ A, const unsigned short* __restrict__ BT,
    void* __restrict__ Cout, const float* __restrict__ R, int M, int N, int Kd) {
  __shared__ __align__(16) unsigned short As[128 * 32];
  __shared__ __align__(16) unsigned short Bs[128 * 32];
  const int t = threadIdx.x;
  const int wave = t >> 6, lane = t & 63;
  const int m0 = blockIdx.y * 128, n0 = blockIdx.x * 128;
  const int wr = wave >> 1, wc = wave & 1;
  const int lr = lane & 15, lg = lane >> 4;

  f32x4 acc[4][4] = {};

  const int srow = 32 * wave + (lane >> 2);
  const int schunk = (lane & 3) * 8;
  const unsigned short* Ag = A + (long)(m0 + srow) * Kd + schunk;
  const unsigned short* Bg = BT + (long)(n0 + srow) * Kd + schunk;
  unsigned short* AsW = &As[(32 * wave) * 32];
  unsigned short* BsW = &Bs[(32 * wave) * 32];

  for (int k0 = 0; k0 < Kd; k0 += 32) {
    __syncthreads();
    gload_lds16(Ag + k0, AsW);
    gload_lds16(Ag + k0 + 16 * (long)Kd, AsW + 16 * 32);
    gload_lds16(Bg + k0, BsW);
    gload_lds16(Bg + k0 + 16 * (long)Kd, BsW + 16 * 32);
    asm volatile("s_waitcnt vmcnt(0)" ::: "memory");
    __syncthreads();

    bf16x8 af[4], bfr[4];
#pragma unroll
    for (int mf = 0; mf < 4; mf++)
      af[mf] = *(const bf16x8*)&As[(64 * wr + 16 * mf + lr) * 32 + lg * 8];
#pragma unroll
    for (int nf = 0; nf < 4; nf++)
      bfr[nf] = *(const bf16x8*)&Bs[(64 * wc + 16 * nf + lr) * 32 + lg * 8];
#pragma unroll
    for (int mf = 0; mf < 4; mf++)
#pragma unroll
      for (int nf = 0; nf < 4; nf++)
        acc[mf][nf] = __builtin_amdgcn_mfma_f32_16x16x32_bf16(af[mf], bfr[nf], acc[mf][nf], 0, 0, 0);
  }

#pragma unroll
  for (int mf = 0; mf < 4; mf++)
#pragma unroll
    for (int nf = 0; nf < 4; nf++)
#pragma unroll
      for (int r = 0; r < 4; r++) {
        const int row = m0 + 64 * wr + 16 * mf + 4 * lg + r;
        const int col = n0 + 64 * wc + 16 * nf + lr;
        const long off = (long)row * N + col;
        float v = acc[mf][nf][r];
        if constexpr (EPI == 1) {
          ((float*)Cout)[off] = v + R[off];
        } else if constexpr (EPI == 2) {
          float gl = 0.5f * v * (1.0f + erff(v * 0.70710678118654752f));
          ((unsigned short*)Cout)[off] = f2bf(gl);
        } else {
          ((float*)Cout)[off] = v;
        }
      }
}

// ---------------- RoPE + split QKV (+ scale q by 1/8) ------------------------
// q part: rows 0..2047 (l*4+b), writes qh f32.  k part: rows 0..3071, writes kb bf16.
// v part: rows 0..3071 cols 2048.., writes vb bf16 (plain convert).
__global__ __launch_bounds__(256) void rope_split(
    const float* __restrict__ QKV, const int* __restrict__ pos_ids, const int* __restrict__ oc,
    float* __restrict__ qh, unsigned short* __restrict__ kb, unsigned short* __restrict__ vb) {
  int idx = blockIdx.x * 256 + threadIdx.x;  // total 4194304
  if (idx < 1048576 + 1572864) {
    bool isq = idx < 1048576;
    int rp = isq ? idx : idx - 1048576;
    int p = rp & 511;
    int row = rp >> 9;
    int hh = p >> 5, dp = p & 31;
    int srow = row >> 2, b = row & 3;
    int pos;
    if (isq) pos = pos_ids[b * 512 + srow];
    else pos = (srow < 512) ? pos_ids[b * 512 + srow]
                            : pos_ids[b * 512 + oc[b * 256 + srow - 512]];
    const float* src = QKV + (long)row * 3072 + (isq ? 0 : 1024) + hh * 64 + dp;
    float x1 = src[0], x2 = src[32];
    float invf = exp2f((float)dp * -0.41524101186091903f);  // 10000^(-dp/32)
    float ang = (float)pos * invf;
    float sn = sinf(ang), cs = cosf(ang);
    float o1 = x1 * cs - x2 * sn, o2 = x1 * sn + x2 * cs;
    if (isq) {
      float* dst = qh + (long)row * 1024 + hh * 64 + dp;
      dst[0] = o1 * 0.125f; dst[32] = o2 * 0.125f;
    } else {
      unsigned short* dst = kb + (long)row * 1024 + hh * 64 + dp;
      dst[0] = f2bf(o1); dst[32] = f2bf(o2);
    }
  } else {
    int rp = idx - (1048576 + 1572864);
    int row = rp >> 9, p = rp & 511;
    const float* src = QKV + (long)row * 3072 + 2048;
    vb[(long)row * 1024 + p] = f2bf(src[p]);
    vb[(long)row * 1024 + p + 512] = f2bf(src[p + 512]);
  }
}

// ---------------- attention: block = (b,h, 16 queries) -----------------------
#define SSTR 776
__global__ __launch_bounds__(256) void att_kernel(
    const float* __restrict__ qh, const unsigned short* __restrict__ kb,
    const unsigned short* __restrict__ vb,
    const unsigned char* __restrict__ pad_mask, const unsigned char* __restrict__ exp_mask,
    unsigned short* __restrict__ o_bf) {
  const int b = blockIdx.y >> 4, h = blockIdx.y & 15;
  const int q0 = blockIdx.x * 16;
  const int t = threadIdx.x;
  __shared__ __align__(16) float Qs[16][65];
  __shared__ __align__(16) float S[16][SSTR];
  __shared__ __align__(16) unsigned short KV[64][68];
  __shared__ float inv[16];

  for (int i = t; i < 1024; i += 256) {
    int r = i >> 6, d = i & 63;
    Qs[r][d] = qh[(((long)(q0 + r) * 4 + b) * 16 + h) * 64 + d];
  }

  const int r1 = t >> 4, ks = t & 15;
  for (int kt = 0; kt < 12; kt++) {
    __syncthreads();
    for (int i = t; i < 1024; i += 256) {  // stage 64x64 bf16 K tile (uint2 copies)
      int kk = i >> 4, c8 = i & 15;
      uint2 u = *(const uint2*)&kb[((((long)(kt * 64 + kk)) * 4 + b) * 16 + h) * 64 + c8 * 4];
      *(uint2*)((char*)&KV[0][0] + kk * 136 + c8 * 8) = u;
    }
    __syncthreads();
#pragma unroll
    for (int ki = 0; ki < 4; ki++) {
      int kk = ks + 16 * ki;
      int key = kt * 64 + kk;
      float acc = 0.f;
      const unsigned int* kr = (const unsigned int*)&KV[kk][0];
      for (int d2 = 0; d2 < 32; d2++) {
        unsigned int u = kr[d2];
        acc += Qs[r1][2 * d2] * __uint_as_float(u << 16)
             + Qs[r1][2 * d2 + 1] * __uint_as_float(u & 0xffff0000u);
      }
      bool m = (key < 512) ? (pad_mask[b * 512 + key] != 0)
                           : (exp_mask[b * 256 + key - 512] != 0);
      S[r1][key] = m ? -1e9f : acc;  // q pre-scaled by 1/sqrt(64)
    }
  }
  __syncthreads();
  {  // softmax over 768 keys, 16 lanes per row
    const int wave = t >> 6, lane = t & 63;
    const int rr = wave * 4 + (lane >> 4);
    const int cs = lane & 15;
    float mx = -3e38f;
    for (int j = 0; j < 48; j++) mx = fmaxf(mx, S[rr][cs + 16 * j]);
#pragma unroll
    for (int o = 1; o < 16; o <<= 1) mx = fmaxf(mx, __shfl_xor(mx, o, 16));
    float sum = 0.f;
    for (int j = 0; j < 48; j++) {
      float p = __expf(S[rr][cs + 16 * j] - mx);
      S[rr][cs + 16 * j] = p; sum += p;
    }
#pragma unroll
    for (int o = 1; o < 16; o <<= 1) sum += __shfl_xor(sum, o, 16);
    if (cs == 0) inv[rr] = 1.0f / sum;
  }
  const int r3 = t >> 4, ds = t & 15;
  float o0 = 0.f, o1 = 0.f, o2 = 0.f, o3 = 0.f;
  for (int vt = 0; vt < 12; vt++) {
    __syncthreads();
    for (int i = t; i < 1024; i += 256) {  // stage 64x64 bf16 V tile
      int kk = i >> 4, c8 = i & 15;
      uint2 u = *(const uint2*)&vb[((((long)(vt * 64 + kk)) * 4 + b) * 16 + h) * 64 + c8 * 4];
      *(uint2*)((char*)&KV[0][0] + kk * 136 + c8 * 8) = u;
    }
    __syncthreads();
    for (int kk = 0; kk < 64; kk++) {
      float p = S[r3][vt * 64 + kk];
      const unsigned int* vr = (const unsigned int*)((const char*)&KV[0][0] + kk * 136 + ds * 8);
      unsigned int ua = vr[0], ub = vr[1];
      o0 += p * __uint_as_float(ua << 16);
      o1 += p * __uint_as_float(ua & 0xffff0000u);
      o2 += p * __uint_as_float(ub << 16);
      o3 += p * __uint_as_float(ub & 0xffff0000u);
    }
  }
  float iv = inv[r3];
  int l = q0 + r3;
  unsigned short* op = o_bf + (((long)l * 4 + b) * 16 + h) * 64 + ds * 4;
  op[0] = f2bf(o0 * iv); op[1] = f2bf(o1 * iv); op[2] = f2bf(o2 * iv); op[3] = f2bf(o3 * iv);
}

// ---------------- pair head: LN'd x @ w1 -> silu -> @ w2 ---------------------
__global__ __launch_bounds__(256) void pair_head(
    const unsigned short* __restrict__ pln, const float* __restrict__ w1,
    const float* __restrict__ w2, float* __restrict__ xpi) {
  const int row = blockIdx.x, t = threadIdx.x;
  __shared__ float red[64][4];
  __shared__ float s1[64];
  const int c = t & 63, qt = t >> 6;
  const unsigned short* xr = pln + (long)row * 1024;
  float acc = 0.f;
  for (int k = qt * 256; k < qt * 256 + 256; k++)
    acc += bf2f(xr[k]) * w1[k * 64 + c];
  red[c][qt] = acc;
  __syncthreads();
  if (t < 64) {
    float v = red[t][0] + red[t][1] + red[t][2] + red[t][3];
    s1[t] = v / (1.f + __expf(-v));  // silu
  }
  __syncthreads();
  if (t < 32) {
    float o = 0.f;
    for (int k = 0; k < 64; k++) o += s1[k] * w2[k * 32 + t];
    xpi[(long)row * 32 + t] = o;
  }
}

__global__ __launch_bounds__(256) void gather_xpj(
    const float* __restrict__ xpi, const int* __restrict__ oc, float* __restrict__ xpj) {
  int idx = blockIdx.x * 256 + threadIdx.x;  // 768*4*32 = 98304
  int hh = idx & 31, rb = idx >> 5;
  int s = rb >> 2, b = rb & 3;
  int src = (s < 512) ? s : oc[b * 256 + s - 512];
  xpj[idx] = xpi[((long)src * 4 + b) * 32 + hh];
}

// ---------------- x_pair += outer(x_p_i, x_p_j) ------------------------------
__global__ __launch_bounds__(256) void pair_update(
    const float* __restrict__ x_pair, const float* __restrict__ xpi,
    const float* __restrict__ xpj, float* __restrict__ out) {
  int idx4 = blockIdx.x * 256 + threadIdx.x;  // 12582912 float4s
  int h4 = idx4 & 7;
  int lkb = idx4 >> 3;  // l*768*4 + kk*4 + b
  int b = lkb & 3;
  int lk = lkb >> 2;
  int kk = lk % 768;
  int l = lk / 768;
  float4 pv = ((const float4*)x_pair)[idx4];
  float4 a = ((const float4*)xpi)[(l * 4 + b) * 8 + h4];
  float4 bb = ((const float4*)xpj)[(kk * 4 + b) * 8 + h4];
  float4 o;
  o.x = pv.x + a.x * bb.x; o.y = pv.y + a.y * bb.y;
  o.z = pv.z + a.z * bb.z; o.w = pv.w + a.w * bb.w;
  ((float4*)out)[idx4] = o;
}

// =============================== launcher ====================================
extern "C" void kernel_launch(void* const* d_in, const int* in_sizes, int n_in,
                              void* d_out, int out_size, void* d_ws, size_t ws_size,
                              hipStream_t stream) {
  const float* x        = (const float*)d_in[0];
  const float* x_pair   = (const float*)d_in[1];
  const unsigned char* pad_mask = (const unsigned char*)d_in[2];
  const unsigned char* exp_mask = (const unsigned char*)d_in[3];
  const int* pos_ids    = (const int*)d_in[4];
  const int* oc         = (const int*)d_in[5];
  const float* wq  = (const float*)d_in[6];
  const float* wk  = (const float*)d_in[7];
  const float* wv  = (const float*)d_in[8];
  const float* wo  = (const float*)d_in[9];
  const float* fc1 = (const float*)d_in[10];
  const float* fc2 = (const float*)d_in[11];
  const float* tln_g = (const float*)d_in[12];
  const float* tln_b = (const float*)d_in[13];
  const float* mln_g = (const float*)d_in[14];
  const float* mln_b = (const float*)d_in[15];
  const float* pln_g = (const float*)d_in[16];
  const float* pln_b = (const float*)d_in[17];
  const float* w1 = (const float*)d_in[18];
  const float* w2 = (const float*)d_in[19];

  char* wsp = (char*)d_ws;
  size_t off = 0;
  auto alloc = [&](size_t bytes) -> void* {
    void* p = wsp + off;
    off = (off + bytes + 255) & ~(size_t)255;
    return p;
  };
  unsigned short* qkvT = (unsigned short*)alloc(3072LL * 1024 * 2);
  unsigned short* woT  = (unsigned short*)alloc(1024LL * 1024 * 2);
  unsigned short* fc1T = (unsigned short*)alloc(4096LL * 1024 * 2);
  unsigned short* fc2T = (unsigned short*)alloc(1024LL * 4096 * 2);
  unsigned short* kvb  = (unsigned short*)alloc(3072LL * 1024 * 2);
  float* QKVb          = (float*)alloc(3072LL * 3072 * 4);
  float* qh            = (float*)alloc(2048LL * 1024 * 4);
  unsigned short* kb   = (unsigned short*)alloc(3072LL * 1024 * 2);
  unsigned short* vbuf = (unsigned short*)alloc(3072LL * 1024 * 2);
  unsigned short* obf  = (unsigned short*)alloc(2048LL * 1024 * 2);
  float* x1            = (float*)alloc(2048LL * 1024 * 4);
  unsigned short* h2   = (unsigned short*)alloc(2048LL * 1024 * 2);
  unsigned short* gbf  = (unsigned short*)alloc(2048LL * 4096 * 2);
  unsigned short* plnb = (unsigned short*)alloc(2048LL * 1024 * 2);
  float* xpi           = (float*)alloc(2048LL * 32 * 4);
  float* xpj           = (float*)alloc(3072LL * 32 * 4);
  (void)ws_size; (void)in_sizes; (void)n_in; (void)out_size;

  dim3 tb(32, 8);
  // weight transposes -> bf16 (NT GEMM B operands)
  transpose_bf16<<<dim3(32, 32), tb, 0, stream>>>(wq, qkvT, 1024, 1024);
  transpose_bf16<<<dim3(32, 32), tb, 0, stream>>>(wk, qkvT + 1024LL * 1024, 1024, 1024);
  transpose_bf16<<<dim3(32, 32), tb, 0, stream>>>(wv, qkvT + 2048LL * 1024, 1024, 1024);
  transpose_bf16<<<dim3(32, 32), tb, 0, stream>>>(wo, woT, 1024, 1024);
  transpose_bf16<<<dim3(128, 32), tb, 0, stream>>>(fc1, fc1T, 1024, 4096);
  transpose_bf16<<<dim3(32, 128), tb, 0, stream>>>(fc2, fc2T, 4096, 1024);

  // top LN -> kv_src rows [0,2048), then gather expanded rows
  ln_bf16<<<2048, 256, 0, stream>>>(x, kvb, tln_g, tln_b);
  gather_kv<<<1024, 256, 0, stream>>>(kvb, oc);

  // fused QKV GEMM: [3072 x 3072] = kv_src @ [wq|wk|wv]
  gemm_nt<0><<<dim3(24, 24), 256, 0, stream>>>(kvb, qkvT, QKVb, nullptr, 3072, 3072, 1024);

  // RoPE + split (q scaled by 1/8)
  rope_split<<<16384, 256, 0, stream>>>(QKVb, pos_ids, oc, qh, kb, vbuf);

  // attention
  att_kernel<<<dim3(32, 64), 256, 0, stream>>>(qh, kb, vbuf, pad_mask, exp_mask, obf);

  // x1 = x + attn_out @ wo
  gemm_nt<1><<<dim3(8, 16), 256, 0, stream>>>(obf, woT, x1, x, 2048, 1024, 1024);

  // FFN
  ln_bf16<<<2048, 256, 0, stream>>>(x1, h2, mln_g, mln_b);
  gemm_nt<2><<<dim3(32, 16), 256, 0, stream>>>(h2, fc1T, gbf, nullptr, 2048, 4096, 1024);
  gemm_nt<1><<<dim3(8, 16), 256, 0, stream>>>(gbf, fc2T, d_out, x1, 2048, 1024, 4096);

  // pair head
  ln_bf16<<<2048, 256, 0, stream>>>((const float*)d_out, plnb, pln_g, pln_b);
  pair_head<<<2048, 256, 0, stream>>>(plnb, w1, w2, xpi);
  gather_xpj<<<384, 256, 0, stream>>>(xpi, oc, xpj);
  pair_update<<<49152, 256, 0, stream>>>(x_pair, xpi, xpj, (float*)d_out + 2097152);
}

// Round 2
// 382.397 us; speedup vs baseline: 7.7924x; 7.7924x over previous
//
#include <hip/hip_runtime.h>
#include <math.h>

// Shapes (fixed): L=512 B=4 D=1024 H=16 DH=64 FF=4096 HP=32 K=256, LK=768

typedef __bf16 bf16x8 __attribute__((ext_vector_type(8)));
typedef float f32x4 __attribute__((ext_vector_type(4)));

__device__ __forceinline__ unsigned short f2bf(float f) {
  unsigned u = __float_as_uint(f);
  u = (u + 0x7fffu + ((u >> 16) & 1u)) >> 16;
  return (unsigned short)u;
}
__device__ __forceinline__ float bf2f(unsigned short s) {
  return __uint_as_float(((unsigned)s) << 16);
}

__device__ __forceinline__ void gload_lds16(const void* g, void* l) {
  __builtin_amdgcn_global_load_lds(
      (__attribute__((address_space(1))) void*)g,
      (__attribute__((address_space(3))) void*)l, 16, 0, 0);
}

// ---------------- transpose f32 -> bf16 (for NT GEMM B operands) -------------
__global__ __launch_bounds__(256) void transpose_bf16(
    const float* __restrict__ W, unsigned short* __restrict__ WT, int Kd, int Nd) {
  __shared__ float tile[32][33];
  const int n0 = blockIdx.x * 32, k0 = blockIdx.y * 32;
  const int tx = threadIdx.x, ty = threadIdx.y;  // 32 x 8
#pragma unroll
  for (int i = 0; i < 32; i += 8)
    tile[ty + i][tx] = W[(long)(k0 + ty + i) * Nd + n0 + tx];
  __syncthreads();
#pragma unroll
  for (int i = 0; i < 32; i += 8)
    WT[(long)(n0 + ty + i) * Kd + k0 + tx] = f2bf(tile[tx][ty + i]);
}

// ---------------- LayerNorm (f32 in, bf16 out), row = 1024 -------------------
__global__ __launch_bounds__(256) void ln_bf16(
    const float* __restrict__ X, unsigned short* __restrict__ Y,
    const float* __restrict__ g, const float* __restrict__ bb) {
  const int row = blockIdx.x, t = threadIdx.x;
  const float* xr = X + (long)row * 1024;
  float v[4]; float s = 0.f, ss = 0.f;
#pragma unroll
  for (int i = 0; i < 4; i++) { v[i] = xr[t + 256 * i]; s += v[i]; ss += v[i] * v[i]; }
#pragma unroll
  for (int o = 32; o > 0; o >>= 1) { s += __shfl_down(s, o); ss += __shfl_down(ss, o); }
  __shared__ float red[8];
  const int wave = t >> 6, lane = t & 63;
  if (lane == 0) { red[wave] = s; red[4 + wave] = ss; }
  __syncthreads();
  s = red[0] + red[1] + red[2] + red[3];
  ss = red[4] + red[5] + red[6] + red[7];
  const float mean = s * (1.f / 1024.f);
  const float rstd = rsqrtf(ss * (1.f / 1024.f) - mean * mean + 1e-5f);
#pragma unroll
  for (int i = 0; i < 4; i++) {
    const int c = t + 256 * i;
    Y[(long)row * 1024 + c] = f2bf((v[i] - mean) * rstd * g[c] + bb[c]);
  }
}

// -------- gather expanded rows of kv_src (bf16), rows [2048, 3072) -----------
__global__ __launch_bounds__(256) void gather_kv(unsigned short* kv, const int* __restrict__ oc) {
  int idx = blockIdx.x * 256 + threadIdx.x;  // 1024 rows * 256 ushort4 = 262144
  int col4 = idx & 255;
  int r = idx >> 8;        // 0..1023 = j*4+b
  int j = r >> 2, b = r & 3;
  int src = oc[b * 256 + j] * 4 + b;
  ((ushort4*)kv)[((512 + j) * 4 + b) * 256 + col4] = ((const ushort4*)kv)[src * 256 + col4];
}

// ---------------- MFMA bf16 NT GEMM, 128x128 tile, BK=32 (m97 structure) -----
template <int EPI>
__global__ __launch_bounds__(256) void gemm_nt(
    const unsigned short* __restrict__ A, const unsigned short* __restrict__ BT,
    void* __restrict__ Cout, const float* __restrict__ R, int M, int N, int Kd) {
  __shared__ __align__(16) unsigned short As[128 * 32];
  __shared__ __align__(16) unsigned short Bs[128 * 32];
  const int t = threadIdx.x;
  const int wave = t >> 6, lane = t & 63;
  const int m0 = blockIdx.y * 128, n0 = blockIdx.x * 128;
  const int wr = wave >> 1, wc = wave & 1;
  const int lr = lane & 15, lg = lane >> 4;

  f32x4 acc[4][4] = {};

  const int srow = 32 * wave + (lane >> 2);
  const int schunk = (lane & 3) * 8;
  const unsigned short* Ag = A + (long)(m0 + srow) * Kd + schunk;
  const unsigned short* Bg = BT + (long)(n0 + srow) * Kd + schunk;
  unsigned short* AsW = &As[(32 * wave) * 32];
  unsigned short* BsW = &Bs[(32 * wave) * 32];

  for (int k0 = 0; k0 < Kd; k0 += 32) {
    __syncthreads();
    gload_lds16(Ag + k0, AsW);
    gload_lds16(Ag + k0 + 16 * (long)Kd, AsW + 16 * 32);
    gload_lds16(Bg + k0, BsW);
    gload_lds16(Bg + k0 + 16 * (long)Kd, BsW + 16 * 32);
    asm volatile("s_waitcnt vmcnt(0)" ::: "memory");
    __syncthreads();

    bf16x8 af[4], bfr[4];
#pragma unroll
    for (int mf = 0; mf < 4; mf++)
      af[mf] = *(const bf16x8*)&As[(64 * wr + 16 * mf + lr) * 32 + lg * 8];
#pragma unroll
    for (int nf = 0; nf < 4; nf++)
      bfr[nf] = *(const bf16x8*)&Bs[(64 * wc + 16 * nf + lr) * 32 + lg * 8];
#pragma unroll
    for (int mf = 0; mf < 4; mf++)
#pragma unroll
      for (int nf = 0; nf < 4; nf++)
        acc[mf][nf] = __builtin_amdgcn_mfma_f32_16x16x32_bf16(af[mf], bfr[nf], acc[mf][nf], 0, 0, 0);
  }

#pragma unroll
  for (int mf = 0; mf < 4; mf++)
#pragma unroll
    for (int nf = 0; nf < 4; nf++)
#pragma unroll
      for (int r = 0; r < 4; r++) {
        const int row = m0 + 64 * wr + 16 * mf + 4 * lg + r;
        const int col = n0 + 64 * wc + 16 * nf + lr;
        const long off = (long)row * N + col;
        float v = acc[mf][nf][r];
        if constexpr (EPI == 1) {
          ((float*)Cout)[off] = v + R[off];
        } else if constexpr (EPI == 2) {
          float gl = 0.5f * v * (1.0f + erff(v * 0.70710678118654752f));
          ((unsigned short*)Cout)[off] = f2bf(gl);
        } else {
          ((float*)Cout)[off] = v;
        }
      }
}

// ---------------- RoPE + split to per-head layouts ---------------------------
// qb:  [bh][512][64] bf16, scaled by 1/8.   kbh: [bh][768][64] bf16.
__global__ __launch_bounds__(256) void rope_split2(
    const float* __restrict__ QKV, const int* __restrict__ pos_ids, const int* __restrict__ oc,
    unsigned short* __restrict__ qb, unsigned short* __restrict__ kbh) {
  int idx = blockIdx.x * 256 + threadIdx.x;  // 1048576 + 1572864
  bool isq = idx < 1048576;
  int rp = isq ? idx : idx - 1048576;
  int p = rp & 511;
  int row = rp >> 9;
  int hh = p >> 5, dp = p & 31;
  int s = row >> 2, b = row & 3;
  int pos = isq ? pos_ids[b * 512 + s]
                : ((s < 512) ? pos_ids[b * 512 + s]
                             : pos_ids[b * 512 + oc[b * 256 + s - 512]]);
  const float* src = QKV + (long)row * 3072 + (isq ? 0 : 1024) + hh * 64 + dp;
  float x1 = src[0], x2 = src[32];
  float invf = exp2f((float)dp * -0.41524101186091903f);  // 10000^(-dp/32)
  float ang = (float)pos * invf;
  float sn = sinf(ang), cs = cosf(ang);
  float o1 = x1 * cs - x2 * sn, o2 = x1 * sn + x2 * cs;
  if (isq) {
    unsigned short* dst = qb + ((long)(b * 16 + hh) * 512 + s) * 64 + dp;
    dst[0] = f2bf(o1 * 0.125f); dst[32] = f2bf(o2 * 0.125f);
  } else {
    unsigned short* dst = kbh + ((long)(b * 16 + hh) * 768 + s) * 64 + dp;
    dst[0] = f2bf(o1); dst[32] = f2bf(o2);
  }
}

// ---------------- V: QKV f32 -> vth bf16 transposed [bh][64 d][768 key] ------
__global__ __launch_bounds__(256) void v_transpose(
    const float* __restrict__ QKV, unsigned short* __restrict__ vth) {
  const int kt = blockIdx.x, bh = blockIdx.y;
  const int b = bh >> 4, h = bh & 15;
  __shared__ unsigned short tile[64][72];
  const int t = threadIdx.x;
  const int key = t >> 2, c = t & 3;
  const float* src = QKV + ((long)(kt * 64 + key) * 4 + b) * 3072 + 2048 + h * 64 + c * 16;
#pragma unroll
  for (int j = 0; j < 16; j++) tile[c * 16 + j][key] = f2bf(src[j]);
  __syncthreads();
  const int d = t >> 2;
  unsigned short* dst = vth + ((long)bh * 64 + d) * 768 + kt * 64 + c * 16;
  *(uint4*)dst = *(const uint4*)&tile[d][c * 16];
  *(uint4*)(dst + 8) = *(const uint4*)&tile[d][c * 16 + 8];
}

// ---------------- MFMA flash attention: block = (b,h, 64 queries) ------------
__global__ __launch_bounds__(256) void att_mfma(
    const unsigned short* __restrict__ qb, const unsigned short* __restrict__ kbh,
    const unsigned short* __restrict__ vth,
    const unsigned char* __restrict__ pad_mask, const unsigned char* __restrict__ exp_mask,
    unsigned short* __restrict__ o_bf) {
  const int bh = blockIdx.y, b = bh >> 4, h = bh & 15;
  const int q0 = blockIdx.x * 64;
  const int t = threadIdx.x, wave = t >> 6, lane = t & 63;
  const int lr = lane & 15, lg = lane >> 4;

  __shared__ __align__(16) unsigned short Qs[64][72];
  __shared__ __align__(16) unsigned short Ks[64][72];
  __shared__ __align__(16) unsigned short Vs[64][72];   // VT tile: [d][key]
  __shared__ __align__(16) unsigned short Ps[4][16][72];
  __shared__ float maskAdd[768];

  {  // stage Q once (rows 64 x 128B)
    const int row = t >> 2, c = t & 3;
    const uint4* src = (const uint4*)(qb + ((long)bh * 512 + q0 + row) * 64 + c * 16);
    *(uint4*)&Qs[row][c * 16] = src[0];
    *(uint4*)&Qs[row][c * 16 + 8] = src[1];
  }
  for (int i = t; i < 768; i += 256)
    maskAdd[i] = ((i < 512) ? pad_mask[b * 512 + i] : exp_mask[b * 256 + i - 512]) ? -1e9f : 0.f;
  __syncthreads();

  const bf16x8 aq0 = *(const bf16x8*)&Qs[wave * 16 + lr][lg * 8];
  const bf16x8 aq1 = *(const bf16x8*)&Qs[wave * 16 + lr][32 + lg * 8];

  float m_run[4] = {-1e30f, -1e30f, -1e30f, -1e30f};
  float l_run[4] = {0.f, 0.f, 0.f, 0.f};
  f32x4 Oacc[4] = {};

  for (int kt = 0; kt < 12; ++kt) {
    __syncthreads();
    {  // stage K tile and VT tile
      const int row = t >> 2, c = t & 3;
      const uint4* ksrc = (const uint4*)(kbh + ((long)bh * 768 + kt * 64 + row) * 64 + c * 16);
      *(uint4*)&Ks[row][c * 16] = ksrc[0];
      *(uint4*)&Ks[row][c * 16 + 8] = ksrc[1];
      const uint4* vsrc = (const uint4*)(vth + ((long)bh * 64 + row) * 768 + kt * 64 + c * 16);
      *(uint4*)&Vs[row][c * 16] = vsrc[0];
      *(uint4*)&Vs[row][c * 16 + 8] = vsrc[1];
    }
    __syncthreads();

    // QK^T: S[16 q][64 key] per wave
    float sv[4][4];
#pragma unroll
    for (int nf = 0; nf < 4; nf++) {
      f32x4 z = {};
      bf16x8 b0 = *(const bf16x8*)&Ks[nf * 16 + lr][lg * 8];
      bf16x8 b1 = *(const bf16x8*)&Ks[nf * 16 + lr][32 + lg * 8];
      z = __builtin_amdgcn_mfma_f32_16x16x32_bf16(aq0, b0, z, 0, 0, 0);
      z = __builtin_amdgcn_mfma_f32_16x16x32_bf16(aq1, b1, z, 0, 0, 0);
      float ma = maskAdd[kt * 64 + nf * 16 + lr];
#pragma unroll
      for (int r = 0; r < 4; r++) sv[nf][r] = z[r] + ma;
    }
    // online softmax (row = lg*4+r within wave's 16)
    float mnew[4], scale[4], rs[4];
#pragma unroll
    for (int r = 0; r < 4; r++) {
      float tm = fmaxf(fmaxf(sv[0][r], sv[1][r]), fmaxf(sv[2][r], sv[3][r]));
      tm = fmaxf(tm, __shfl_xor(tm, 1));
      tm = fmaxf(tm, __shfl_xor(tm, 2));
      tm = fmaxf(tm, __shfl_xor(tm, 4));
      tm = fmaxf(tm, __shfl_xor(tm, 8));
      mnew[r] = fmaxf(m_run[r], tm);
      scale[r] = __expf(m_run[r] - mnew[r]);
      m_run[r] = mnew[r];
      rs[r] = 0.f;
    }
#pragma unroll
    for (int nf = 0; nf < 4; nf++)
#pragma unroll
      for (int r = 0; r < 4; r++) {
        float p = __expf(sv[nf][r] - mnew[r]);
        rs[r] += p;
        Ps[wave][lg * 4 + r][nf * 16 + lr] = f2bf(p);
      }
#pragma unroll
    for (int r = 0; r < 4; r++) {
      float x = rs[r];
      x += __shfl_xor(x, 1); x += __shfl_xor(x, 2);
      x += __shfl_xor(x, 4); x += __shfl_xor(x, 8);
      l_run[r] = l_run[r] * scale[r] + x;
#pragma unroll
      for (int nf = 0; nf < 4; nf++) Oacc[nf][r] *= scale[r];
    }
    // PV: O[16 q][64 d] += P @ V   (A = Ps rows, BT = Vs rows; within-wave dep on Ps)
    bf16x8 ap0 = *(const bf16x8*)&Ps[wave][lr][lg * 8];
    bf16x8 ap1 = *(const bf16x8*)&Ps[wave][lr][32 + lg * 8];
#pragma unroll
    for (int nf = 0; nf < 4; nf++) {
      bf16x8 b0 = *(const bf16x8*)&Vs[nf * 16 + lr][lg * 8];
      bf16x8 b1 = *(const bf16x8*)&Vs[nf * 16 + lr][32 + lg * 8];
      Oacc[nf] = __builtin_amdgcn_mfma_f32_16x16x32_bf16(ap0, b0, Oacc[nf], 0, 0, 0);
      Oacc[nf] = __builtin_amdgcn_mfma_f32_16x16x32_bf16(ap1, b1, Oacc[nf], 0, 0, 0);
    }
  }

#pragma unroll
  for (int r = 0; r < 4; r++) {
    float inv = 1.0f / l_run[r];
    int l = q0 + wave * 16 + lg * 4 + r;
#pragma unroll
    for (int nf = 0; nf < 4; nf++)
      o_bf[(((long)l * 4 + b) * 16 + h) * 64 + nf * 16 + lr] = f2bf(Oacc[nf][r] * inv);
  }
}

// ---------------- pair head: LN'd x @ w1 -> silu -> @ w2 ---------------------
__global__ __launch_bounds__(256) void pair_head(
    const unsigned short* __restrict__ pln, const float* __restrict__ w1,
    const float* __restrict__ w2, float* __restrict__ xpi) {
  const int row = blockIdx.x, t = threadIdx.x;
  __shared__ float red[64][4];
  __shared__ float s1[64];
  const int c = t & 63, qt = t >> 6;
  const unsigned short* xr = pln + (long)row * 1024;
  float acc = 0.f;
  for (int k = qt * 256; k < qt * 256 + 256; k++)
    acc += bf2f(xr[k]) * w1[k * 64 + c];
  red[c][qt] = acc;
  __syncthreads();
  if (t < 64) {
    float v = red[t][0] + red[t][1] + red[t][2] + red[t][3];
    s1[t] = v / (1.f + __expf(-v));  // silu
  }
  __syncthreads();
  if (t < 32) {
    float o = 0.f;
    for (int k = 0; k < 64; k++) o += s1[k] * w2[k * 32 + t];
    xpi[(long)row * 32 + t] = o;
  }
}

__global__ __launch_bounds__(256) void gather_xpj(
    const float* __restrict__ xpi, const int* __restrict__ oc, float* __restrict__ xpj) {
  int idx = blockIdx.x * 256 + threadIdx.x;  // 768*4*32 = 98304
  int hh = idx & 31, rb = idx >> 5;
  int s = rb >> 2, b = rb & 3;
  int src = (s < 512) ? s : oc[b * 256 + s - 512];
  xpj[idx] = xpi[((long)src * 4 + b) * 32 + hh];
}

// ---------------- x_pair += outer(x_p_i, x_p_j) ------------------------------
__global__ __launch_bounds__(256) void pair_update(
    const float* __restrict__ x_pair, const float* __restrict__ xpi,
    const float* __restrict__ xpj, float* __restrict__ out) {
  int idx4 = blockIdx.x * 256 + threadIdx.x;  // 12582912 float4s
  int h4 = idx4 & 7;
  int lkb = idx4 >> 3;
  int b = lkb & 3;
  int lk = lkb >> 2;
  int kk = lk % 768;
  int l = lk / 768;
  float4 pv = ((const float4*)x_pair)[idx4];
  float4 a = ((const float4*)xpi)[(l * 4 + b) * 8 + h4];
  float4 bb = ((const float4*)xpj)[(kk * 4 + b) * 8 + h4];
  float4 o;
  o.x = pv.x + a.x * bb.x; o.y = pv.y + a.y * bb.y;
  o.z = pv.z + a.z * bb.z; o.w = pv.w + a.w * bb.w;
  ((float4*)out)[idx4] = o;
}

// =============================== launcher ====================================
extern "C" void kernel_launch(void* const* d_in, const int* in_sizes, int n_in,
                              void* d_out, int out_size, void* d_ws, size_t ws_size,
                              hipStream_t stream) {
  const float* x        = (const float*)d_in[0];
  const float* x_pair   = (const float*)d_in[1];
  const unsigned char* pad_mask = (const unsigned char*)d_in[2];
  const unsigned char* exp_mask = (const unsigned char*)d_in[3];
  const int* pos_ids    = (const int*)d_in[4];
  const int* oc         = (const int*)d_in[5];
  const float* wq  = (const float*)d_in[6];
  const float* wk  = (const float*)d_in[7];
  const float* wv  = (const float*)d_in[8];
  const float* wo  = (const float*)d_in[9];
  const float* fc1 = (const float*)d_in[10];
  const float* fc2 = (const float*)d_in[11];
  const float* tln_g = (const float*)d_in[12];
  const float* tln_b = (const float*)d_in[13];
  const float* mln_g = (const float*)d_in[14];
  const float* mln_b = (const float*)d_in[15];
  const float* pln_g = (const float*)d_in[16];
  const float* pln_b = (const float*)d_in[17];
  const float* w1 = (const float*)d_in[18];
  const float* w2 = (const float*)d_in[19];

  char* wsp = (char*)d_ws;
  size_t off = 0;
  auto alloc = [&](size_t bytes) -> void* {
    void* p = wsp + off;
    off = (off + bytes + 255) & ~(size_t)255;
    return p;
  };
  unsigned short* qkvT = (unsigned short*)alloc(3072LL * 1024 * 2);
  unsigned short* woT  = (unsigned short*)alloc(1024LL * 1024 * 2);
  unsigned short* fc1T = (unsigned short*)alloc(4096LL * 1024 * 2);
  unsigned short* fc2T = (unsigned short*)alloc(1024LL * 4096 * 2);
  unsigned short* kvb  = (unsigned short*)alloc(3072LL * 1024 * 2);
  float* QKVb          = (float*)alloc(3072LL * 3072 * 4);
  unsigned short* qb   = (unsigned short*)alloc(64LL * 512 * 64 * 2);
  unsigned short* kbh  = (unsigned short*)alloc(64LL * 768 * 64 * 2);
  unsigned short* vth  = (unsigned short*)alloc(64LL * 64 * 768 * 2);
  unsigned short* obf  = (unsigned short*)alloc(2048LL * 1024 * 2);
  float* x1            = (float*)alloc(2048LL * 1024 * 4);
  unsigned short* h2   = (unsigned short*)alloc(2048LL * 1024 * 2);
  unsigned short* gbf  = (unsigned short*)alloc(2048LL * 4096 * 2);
  unsigned short* plnb = (unsigned short*)alloc(2048LL * 1024 * 2);
  float* xpi           = (float*)alloc(2048LL * 32 * 4);
  float* xpj           = (float*)alloc(3072LL * 32 * 4);
  (void)ws_size; (void)in_sizes; (void)n_in; (void)out_size;

  dim3 tb(32, 8);
  transpose_bf16<<<dim3(32, 32), tb, 0, stream>>>(wq, qkvT, 1024, 1024);
  transpose_bf16<<<dim3(32, 32), tb, 0, stream>>>(wk, qkvT + 1024LL * 1024, 1024, 1024);
  transpose_bf16<<<dim3(32, 32), tb, 0, stream>>>(wv, qkvT + 2048LL * 1024, 1024, 1024);
  transpose_bf16<<<dim3(32, 32), tb, 0, stream>>>(wo, woT, 1024, 1024);
  transpose_bf16<<<dim3(128, 32), tb, 0, stream>>>(fc1, fc1T, 1024, 4096);
  transpose_bf16<<<dim3(32, 128), tb, 0, stream>>>(fc2, fc2T, 4096, 1024);

  ln_bf16<<<2048, 256, 0, stream>>>(x, kvb, tln_g, tln_b);
  gather_kv<<<1024, 256, 0, stream>>>(kvb, oc);

  gemm_nt<0><<<dim3(24, 24), 256, 0, stream>>>(kvb, qkvT, QKVb, nullptr, 3072, 3072, 1024);

  rope_split2<<<10240, 256, 0, stream>>>(QKVb, pos_ids, oc, qb, kbh);
  v_transpose<<<dim3(12, 64), 256, 0, stream>>>(QKVb, vth);

  att_mfma<<<dim3(8, 64), 256, 0, stream>>>(qb, kbh, vth, pad_mask, exp_mask, obf);

  gemm_nt<1><<<dim3(8, 16), 256, 0, stream>>>(obf, woT, x1, x, 2048, 1024, 1024);

  ln_bf16<<<2048, 256, 0, stream>>>(x1, h2, mln_g, mln_b);
  gemm_nt<2><<<dim3(32, 16), 256, 0, stream>>>(h2, fc1T, gbf, nullptr, 2048, 4096, 1024);
  gemm_nt<1><<<dim3(8, 16), 256, 0, stream>>>(gbf, fc2T, d_out, x1, 2048, 1024, 4096);

  ln_bf16<<<2048, 256, 0, stream>>>((const float*)d_out, plnb, pln_g, pln_b);
  pair_head<<<2048, 256, 0, stream>>>(plnb, w1, w2, xpi);
  gather_xpj<<<384, 256, 0, stream>>>(xpi, oc, xpj);
  pair_update<<<49152, 256, 0, stream>>>(x_pair, xpi, xpj, (float*)d_out + 2097152);
}